// Round 15
// baseline (5868.130 us; speedup 1.0000x reference)
//
#include <hip/hip_runtime.h>
#include <hip/hip_bf16.h>

typedef unsigned short u16;
typedef unsigned int u32;
typedef short bf16x8 __attribute__((ext_vector_type(8)));
typedef float f32x4 __attribute__((ext_vector_type(4)));

#define BAR() asm volatile("s_barrier" ::: "memory")
#define WAITV4() asm volatile("s_waitcnt vmcnt(4)" ::: "memory")
#define WAITV0() asm volatile("s_waitcnt vmcnt(0)" ::: "memory")

// ---------- helpers ----------
__device__ __forceinline__ unsigned pk2(float lo, float hi) {
    unsigned a = (unsigned)__builtin_bit_cast(u16, __float2bfloat16(lo));
    unsigned b = (unsigned)__builtin_bit_cast(u16, __float2bfloat16(hi));
    return a | (b << 16);
}
__device__ __forceinline__ u16 f2bf(float v) {
    return __builtin_bit_cast(u16, __float2bfloat16(v));
}
__device__ __forceinline__ void gl_lds16(const u16* g, u16* l) {
    __builtin_amdgcn_global_load_lds(
        (const __attribute__((address_space(1))) u32*)g,
        (__attribute__((address_space(3))) u32*)l, 16, 0, 0);
}

// ---------- f32 -> bf16 weight convert ----------
__global__ void cvtbf(const float4* __restrict__ s, uint2* __restrict__ d, int n4) {
    int i = blockIdx.x * blockDim.x + threadIdx.x;
    int stride = gridDim.x * blockDim.x;
    for (; i < n4; i += stride) {
        float4 f = s[i];
        uint2 o;
        o.x = pk2(f.x, f.y);
        o.y = pk2(f.z, f.w);
        d[i] = o;
    }
}

// ---------- build x = [u_t | emb[s_i]] as bf16 [65536][1536] ----------
__global__ __launch_bounds__(256) void xbuild(const float* __restrict__ u_t,
                                              const float* __restrict__ emb,
                                              const int* __restrict__ s_i,
                                              u16* __restrict__ xb) {
    const long u = (long)blockIdx.x * blockDim.x + threadIdx.x;
    const int row = (int)(u / 192);
    const int c8 = (int)(u % 192);
    const float* src = (c8 < 96) ? (u_t + (long)row * 768 + c8 * 8)
                                 : (emb + (long)s_i[row] * 768 + (c8 - 96) * 8);
    float4 f0 = ((const float4*)src)[0];
    float4 f1 = ((const float4*)src)[1];
    uint4 o;
    o.x = pk2(f0.x, f0.y);
    o.y = pk2(f0.z, f0.w);
    o.z = pk2(f1.x, f1.y);
    o.w = pk2(f1.z, f1.w);
    *(uint4*)(xb + u * 8) = o;
}

// ---------- 256x256 GEMM, BK=32, 64KB dbuf -> 2 blocks/CU ------------------
// A [M][LDK] bf16, B [TN*256][LDK] bf16. EPI 0: tanh-GELU->bf16, EPI 1: bias->f32.
// Occupancy lever (m114/m97): 64 KiB LDS (2 bufs x [A 16K|B 16K]) -> TWO
// co-resident blocks per CU; each block's vmcnt/barrier stalls are filled by
// the other block's MFMA. Per K-tile: {stage t+1 -> buf^1 (4 gl_lds)} ->
// vmcnt(4) [drains t's 4; t+1's stay in flight] -> BAR -> 12 ds_read +
// 32 MFMA/wave -> BAR. Last tile drains vmcnt(0) (R3 lesson).
// LDS rows = 32 u16 (4 x 16B chunks); swizzle c' = c ^ ((row>>1)&3) -> exact
// 2-way bank access (free, m136); applied on global source + ds_read side
// (linear gl_lds dest, rule 21; pass1 row+128 preserves the XOR since 128>>1≡0 mod 4).
template <int LDK, int NT, int TN, int EPI>
__global__ __launch_bounds__(512, 4) void gemm256(
    const u16* __restrict__ Ag, const u16* __restrict__ Bg,
    const float* __restrict__ bias, u16* __restrict__ outb,
    float* __restrict__ outf) {
    __shared__ __align__(16) u16 lds[32768];  // 64 KiB = 2 bufs x 32KB

    const int tid = threadIdx.x;
    const int lane = tid & 63;
    const int wv = tid >> 6;
    const int wm = wv >> 2;  // 0..1
    const int wn = wv & 3;   // 0..3

    const int cpx = (int)gridDim.x >> 3;  // grid % 8 == 0
    const int tile = ((int)blockIdx.x & 7) * cpx + ((int)blockIdx.x >> 3);
    const int tm = tile / TN, tn = tile % TN;
    const long rowBase = (long)tm * 256;
    const long colBase = (long)tn * 256;

    // --- staging map: row = tid>>2 (+128 on pass 1), chunk = tid&3 ---
    const int srow = tid >> 2;
    const int gch = (tid & 3) ^ ((srow >> 1) & 3);
    const u16* pA = Ag + (rowBase + srow) * (long)LDK + gch * 8;
    const u16* pB = Bg + (colBase + srow) * (long)LDK + gch * 8;
    const int dstBase = wv * 512;  // u16; dest linear = tid*16B

    auto stageA = [&](int kt, int b) {
        const u16* s = pA + kt * 32;
        u16* d = lds + b * 16384 + dstBase;
        gl_lds16(s, d);
        gl_lds16(s + (long)128 * LDK, d + 4096);
    };
    auto stageB = [&](int kt, int b) {
        const u16* s = pB + kt * 32;
        u16* d = lds + b * 16384 + 8192 + dstBase;
        gl_lds16(s, d);
        gl_lds16(s + (long)128 * LDK, d + 4096);
    };

    // --- fragment read offsets (u16 units; row stride 32 u16) ---
    const int l15 = lane & 15, lc = lane >> 4;  // lc = k-chunk 0..3
    int offA[8], offB[4];
#pragma unroll
    for (int i = 0; i < 8; ++i) {
        int r = wm * 128 + i * 16 + l15;
        offA[i] = r * 32 + ((lc ^ ((r >> 1) & 3)) << 3);
    }
#pragma unroll
    for (int n = 0; n < 4; ++n) {
        int c = wn * 64 + n * 16 + l15;
        offB[n] = c * 32 + ((lc ^ ((c >> 1) & 3)) << 3);
    }

    f32x4 acc[8][4];
    const f32x4 zero = {0.f, 0.f, 0.f, 0.f};
#pragma unroll
    for (int m = 0; m < 8; ++m)
#pragma unroll
        for (int n = 0; n < 4; ++n) acc[m][n] = zero;

    // --- prologue: stage tile 0 into buf 0 (4 loads) ---
    stageA(0, 0);
    stageB(0, 0);

    for (int kt = 0; kt < NT; ++kt) {
        const int b = kt & 1;
        const bool pf = (kt + 1 < NT);

        // issue next tile into buf^1 (safe: closing BAR of kt-1 guarantees
        // all waves finished reading buf^1's old contents)
        if (pf) { stageA(kt + 1, b ^ 1); stageB(kt + 1, b ^ 1); }
        // drain tile t's 4 loads; t+1's 4 stay in flight (last: drain all)
        if (pf) { WAITV4(); } else { WAITV0(); }
        BAR();

        const u16* rA = lds + b * 16384;
        const u16* rB = rA + 8192;
        bf16x8 xA[8], xB[4];
#pragma unroll
        for (int n = 0; n < 4; ++n) xB[n] = *(const bf16x8*)(rB + offB[n]);
#pragma unroll
        for (int m = 0; m < 8; ++m) xA[m] = *(const bf16x8*)(rA + offA[m]);
        __builtin_amdgcn_s_setprio(1);
#pragma unroll
        for (int m = 0; m < 8; ++m)
#pragma unroll
            for (int n = 0; n < 4; ++n)
                acc[m][n] = __builtin_amdgcn_mfma_f32_16x16x32_bf16(xA[m], xB[n], acc[m][n], 0, 0, 0);
        __builtin_amdgcn_s_setprio(0);
        BAR();  // all waves done reading buf b before it is restaged at kt+2
    }

    // ---- epilogue ----
    const int N = TN * 256;
#pragma unroll
    for (int n = 0; n < 4; ++n) {
        long gc = colBase + wn * 64 + n * 16 + l15;
        float bv = bias[gc];
#pragma unroll
        for (int i = 0; i < 8; ++i) {
            long gr = rowBase + wm * 128 + i * 16 + (lc << 2);
#pragma unroll
            for (int j = 0; j < 4; ++j) {
                float v = acc[i][n][j] + bv;
                if constexpr (EPI == 0) {
                    // gelu(v) = v * sigmoid(2u), u = 0.79788456(v + 0.044715 v^3)
                    float w = v * v;
                    float z = v * fmaf(w, -0.0713548162f, -1.5957691216f);  // -2u
                    v = __fdividef(v, 1.0f + __expf(z));
                    outb[(gr + j) * N + gc] = f2bf(v);
                } else {
                    outf[(gr + j) * N + gc] = v;
                }
            }
        }
    }
}

// ---------- LayerNorm (in place, f32) + scatter-add into updated ----------
__global__ __launch_bounds__(256) void ln_scatter(float* __restrict__ y,
                                                  const float* __restrict__ gamma,
                                                  const float* __restrict__ beta,
                                                  const int* __restrict__ s_i,
                                                  float* __restrict__ upd) {
    const int lane = threadIdx.x & 63;
    const long row = (long)blockIdx.x * 4 + (threadIdx.x >> 6);
    const long base = row * 768;
    float v[12];
#pragma unroll
    for (int i = 0; i < 12; ++i) v[i] = y[base + i * 64 + lane];
    float s = 0.f, q = 0.f;
#pragma unroll
    for (int i = 0; i < 12; ++i) { s += v[i]; q += v[i] * v[i]; }
#pragma unroll
    for (int off = 32; off > 0; off >>= 1) {
        s += __shfl_xor(s, off, 64);
        q += __shfl_xor(q, off, 64);
    }
    const float mu = s * (1.f / 768.f);
    const float var = q * (1.f / 768.f) - mu * mu;
    const float inv = rsqrtf(var + 1e-5f);
    const long si = s_i[row];
#pragma unroll
    for (int i = 0; i < 12; ++i) {
        int c = i * 64 + lane;
        float r = (v[i] - mu) * inv * gamma[c] + beta[c];
        y[base + c] = r;
        atomicAdd(&upd[si * 768 + c], r);
    }
}

// ---------- plain float4 copy ----------
__global__ void copy4(const float4* __restrict__ s, float4* __restrict__ d, long n) {
    long i = (long)blockIdx.x * blockDim.x + threadIdx.x;
    long stride = (long)gridDim.x * blockDim.x;
    for (; i < n; i += stride) d[i] = s[i];
}

extern "C" void kernel_launch(void* const* d_in, const int* in_sizes, int n_in,
                              void* d_out, int out_size, void* d_ws, size_t ws_size,
                              hipStream_t stream) {
    const float* u_t = (const float*)d_in[0];
    const int* s_i = (const int*)d_in[1];
    const float* emb = (const float*)d_in[2];
    const float* W1 = (const float*)d_in[3];
    const float* b1 = (const float*)d_in[4];
    const float* W2 = (const float*)d_in[5];
    const float* b2 = (const float*)d_in[6];
    const float* gamma = (const float*)d_in[7];
    const float* beta = (const float*)d_in[8];

    float* out = (float*)d_out;
    float* newh = out;             // [65536,768] f32 (y, then LN in place) - NOT in upd
    float* upd = out + 50331648L;  // [262144,768] f32 (scratch first, final last)

    // scratch inside upd (all dead before copy4 runs):
    u16* base = (u16*)upd;
    u16* xb = base;                    // [65536,1536] bf16
    u16* w1b = base + 100663296L;      // [2048,1536] bf16
    u16* hbuf = base + 103809024L;     // [65536,2048] bf16
    u16* w2b = base + 238026752L;      // [768,2048] bf16

    cvtbf<<<1024, 256, 0, stream>>>((const float4*)W1, (uint2*)w1b, 786432);
    cvtbf<<<1024, 256, 0, stream>>>((const float4*)W2, (uint2*)w2b, 393216);
    xbuild<<<49152, 256, 0, stream>>>(u_t, emb, s_i, xb);
    // GEMM1: M=65536, N=2048, K=1536 (NT=48) -> 2048 tiles (tanh-GELU, bf16)
    gemm256<1536, 48, 8, 0><<<2048, 512, 0, stream>>>(xb, w1b, b1, hbuf, nullptr);
    // GEMM2: M=65536, N=768, K=2048 (NT=64) -> 768 tiles (bias, f32)
    gemm256<2048, 64, 3, 1><<<768, 512, 0, stream>>>(hbuf, w2b, b2, nullptr, newh);
    copy4<<<2048, 256, 0, stream>>>((const float4*)emb, (float4*)upd, 50331648L);
    ln_scatter<<<16384, 256, 0, stream>>>(newh, gamma, beta, s_i, upd);
}

// Round 16
// 1324.311 us; speedup vs baseline: 4.4311x; 4.4311x over previous
//
#include <hip/hip_runtime.h>
#include <hip/hip_bf16.h>

typedef unsigned short u16;
typedef unsigned int u32;
typedef short bf16x8 __attribute__((ext_vector_type(8)));
typedef float f32x4 __attribute__((ext_vector_type(4)));

#define BAR() asm volatile("s_barrier" ::: "memory")
#define WAITV4() asm volatile("s_waitcnt vmcnt(4)" ::: "memory")
#define WAITV0() asm volatile("s_waitcnt vmcnt(0)" ::: "memory")
#define WAITL() asm volatile("s_waitcnt lgkmcnt(0)" ::: "memory")

// ---------- helpers ----------
__device__ __forceinline__ unsigned pk2(float lo, float hi) {
    unsigned a = (unsigned)__builtin_bit_cast(u16, __float2bfloat16(lo));
    unsigned b = (unsigned)__builtin_bit_cast(u16, __float2bfloat16(hi));
    return a | (b << 16);
}
__device__ __forceinline__ u16 f2bf(float v) {
    return __builtin_bit_cast(u16, __float2bfloat16(v));
}
__device__ __forceinline__ void gl_lds16(const u16* g, u16* l) {
    __builtin_amdgcn_global_load_lds(
        (const __attribute__((address_space(1))) u32*)g,
        (__attribute__((address_space(3))) u32*)l, 16, 0, 0);
}

// ---------- f32 -> bf16 weight convert ----------
__global__ void cvtbf(const float4* __restrict__ s, uint2* __restrict__ d, int n4) {
    int i = blockIdx.x * blockDim.x + threadIdx.x;
    int stride = gridDim.x * blockDim.x;
    for (; i < n4; i += stride) {
        float4 f = s[i];
        uint2 o;
        o.x = pk2(f.x, f.y);
        o.y = pk2(f.z, f.w);
        d[i] = o;
    }
}

// ---------- build x = [u_t | emb[s_i]] as bf16 [65536][1536] ----------
__global__ __launch_bounds__(256) void xbuild(const float* __restrict__ u_t,
                                              const float* __restrict__ emb,
                                              const int* __restrict__ s_i,
                                              u16* __restrict__ xb) {
    const long u = (long)blockIdx.x * blockDim.x + threadIdx.x;
    const int row = (int)(u / 192);
    const int c8 = (int)(u % 192);
    const float* src = (c8 < 96) ? (u_t + (long)row * 768 + c8 * 8)
                                 : (emb + (long)s_i[row] * 768 + (c8 - 96) * 8);
    float4 f0 = ((const float4*)src)[0];
    float4 f1 = ((const float4*)src)[1];
    uint4 o;
    o.x = pk2(f0.x, f0.y);
    o.y = pk2(f0.z, f0.w);
    o.z = pk2(f1.x, f1.y);
    o.w = pk2(f1.z, f1.w);
    *(uint4*)(xb + u * 8) = o;
}

// ---------- 256x256 8-phase GEMM (R8 champion):  out = act(A @ B^T + bias) --
// A [M][LDK] bf16, B [TN*256][LDK] bf16. EPI 0: tanh-GELU->bf16, EPI 1: bias->f32.
// LDS layout: lds[buf][A/B][ks][256*32 u16], swizzled chunks: c' = c ^ ((row>>1)&3),
// applied on global source + ds_read side (linear gl_lds dest, rule 21).
// NOTE (R15 lesson): 8-wave 256^2 tile needs ~216 regs/thread (128 f32 acc) ->
// 1 block/CU is structural; do NOT force higher occupancy via launch_bounds
// (forces 64 VGPR -> acc spills to scratch -> 17 GB HBM traffic, 4.4x slower).
template <int LDK, int NT, int TN, int EPI>
__global__ __launch_bounds__(512, 2) void gemm256(
    const u16* __restrict__ Ag, const u16* __restrict__ Bg,
    const float* __restrict__ bias, u16* __restrict__ outb,
    float* __restrict__ outf) {
    __shared__ __align__(16) u16 lds[65536];  // 128 KiB

    const int tid = threadIdx.x;
    const int lane = tid & 63;
    const int wv = tid >> 6;
    const int wm = wv >> 2;  // 0..1
    const int wn = wv & 3;   // 0..3

    const int cpx = (int)gridDim.x >> 3;  // grid % 8 == 0
    const int tile = ((int)blockIdx.x & 7) * cpx + ((int)blockIdx.x >> 3);
    const int tm = tile / TN, tn = tile % TN;
    const long rowBase = (long)tm * 256;
    const long colBase = (long)tn * 256;

    // --- staging map: thread -> (row = tid>>2 [+128], swizzled 16B chunk) ---
    const int srow = tid >> 2;
    const int gch = (tid & 3) ^ ((tid >> 3) & 3);
    const u16* pA = Ag + (rowBase + srow) * (long)LDK + gch * 8;
    const u16* pB = Bg + (colBase + srow) * (long)LDK + gch * 8;
    const int dstBase = wv * 512;  // u16 units within 8KB sub-block

    auto stageA = [&](int kt, int ks, int b) {
        const u16* s = pA + kt * 64 + ks * 32;
        u16* d = lds + b * 32768 + ks * 8192 + dstBase;
        gl_lds16(s, d);
        gl_lds16(s + (long)128 * LDK, d + 4096);
    };
    auto stageB = [&](int kt, int ks, int b) {
        const u16* s = pB + kt * 64 + ks * 32;
        u16* d = lds + b * 32768 + 16384 + ks * 8192 + dstBase;
        gl_lds16(s, d);
        gl_lds16(s + (long)128 * LDK, d + 4096);
    };

    // --- fragment read offsets (u16 units, relative to 8KB ks-region) ---
    const int l15 = lane & 15, lc = lane >> 4;
    int offA[8], offB[4];
#pragma unroll
    for (int i = 0; i < 8; ++i) {
        int r = wm * 128 + i * 16 + l15;
        offA[i] = r * 32 + ((lc ^ ((r >> 1) & 3)) << 3);
    }
#pragma unroll
    for (int n = 0; n < 4; ++n) {
        int r = wn * 64 + n * 16 + l15;
        offB[n] = r * 32 + ((lc ^ ((r >> 1) & 3)) << 3);
    }

    f32x4 acc[8][4];
    const f32x4 zero = {0.f, 0.f, 0.f, 0.f};
#pragma unroll
    for (int m = 0; m < 8; ++m)
#pragma unroll
        for (int n = 0; n < 4; ++n) acc[m][n] = zero;

    // --- prologue: stage tile 0 fully; wait ks0 halves (ks1 stays in flight) ---
    stageA(0, 0, 0);
    stageB(0, 0, 0);
    stageA(0, 1, 0);
    stageB(0, 1, 0);
    WAITV4();
    BAR();

    bf16x8 bA[4], bB[4];
    for (int kt = 0; kt < NT; ++kt) {
        const int b = kt & 1;
        const u16* rA0 = lds + b * 32768;
        const u16* rB0 = rA0 + 16384;
        const u16* rA1 = rA0 + 8192;
        const u16* rB1 = rB0 + 8192;
        const bool pf = (kt + 1 < NT);

        // ---- P0: ks0, m-half0 (reads B ks0 too) ----
#pragma unroll
        for (int n = 0; n < 4; ++n) bB[n] = *(const bf16x8*)(rB0 + offB[n]);
#pragma unroll
        for (int m = 0; m < 4; ++m) bA[m] = *(const bf16x8*)(rA0 + offA[m]);
        if (pf) stageA(kt + 1, 0, b ^ 1);
        BAR();
        WAITL();
        __builtin_amdgcn_s_setprio(1);
#pragma unroll
        for (int m = 0; m < 4; ++m)
#pragma unroll
            for (int n = 0; n < 4; ++n)
                acc[m][n] = __builtin_amdgcn_mfma_f32_16x16x32_bf16(bA[m], bB[n], acc[m][n], 0, 0, 0);
        __builtin_amdgcn_s_setprio(0);
        BAR();

        // ---- P1: ks0, m-half1 ----
#pragma unroll
        for (int m = 0; m < 4; ++m) bA[m] = *(const bf16x8*)(rA0 + offA[4 + m]);
        if (pf) stageB(kt + 1, 0, b ^ 1);
        BAR();
        WAITL();
        __builtin_amdgcn_s_setprio(1);
#pragma unroll
        for (int m = 0; m < 4; ++m)
#pragma unroll
            for (int n = 0; n < 4; ++n)
                acc[4 + m][n] = __builtin_amdgcn_mfma_f32_16x16x32_bf16(bA[m], bB[n], acc[4 + m][n], 0, 0, 0);
        __builtin_amdgcn_s_setprio(0);
        // tile t ks1 must land. Last tile: nothing newer -> drain (R3 lesson).
        if (pf) { WAITV4(); } else { WAITV0(); }
        BAR();

        // ---- P2: ks1, m-half0 (reads B ks1 too) ----
#pragma unroll
        for (int n = 0; n < 4; ++n) bB[n] = *(const bf16x8*)(rB1 + offB[n]);
#pragma unroll
        for (int m = 0; m < 4; ++m) bA[m] = *(const bf16x8*)(rA1 + offA[m]);
        if (pf) stageA(kt + 1, 1, b ^ 1);
        BAR();
        WAITL();
        __builtin_amdgcn_s_setprio(1);
#pragma unroll
        for (int m = 0; m < 4; ++m)
#pragma unroll
            for (int n = 0; n < 4; ++n)
                acc[m][n] = __builtin_amdgcn_mfma_f32_16x16x32_bf16(bA[m], bB[n], acc[m][n], 0, 0, 0);
        __builtin_amdgcn_s_setprio(0);
        BAR();

        // ---- P3: ks1, m-half1 ----
#pragma unroll
        for (int m = 0; m < 4; ++m) bA[m] = *(const bf16x8*)(rA1 + offA[4 + m]);
        if (pf) stageB(kt + 1, 1, b ^ 1);
        BAR();
        WAITL();
        __builtin_amdgcn_s_setprio(1);
#pragma unroll
        for (int m = 0; m < 4; ++m)
#pragma unroll
            for (int n = 0; n < 4; ++n)
                acc[4 + m][n] = __builtin_amdgcn_mfma_f32_16x16x32_bf16(bA[m], bB[n], acc[4 + m][n], 0, 0, 0);
        __builtin_amdgcn_s_setprio(0);
        if (pf) { WAITV4(); } else { WAITV0(); }
        BAR();
    }

    // ---- epilogue ----
    const int N = TN * 256;
#pragma unroll
    for (int n = 0; n < 4; ++n) {
        long gc = colBase + wn * 64 + n * 16 + l15;
        float bv = bias[gc];
#pragma unroll
        for (int i = 0; i < 8; ++i) {
            long gr = rowBase + wm * 128 + i * 16 + (lc << 2);
#pragma unroll
            for (int j = 0; j < 4; ++j) {
                float v = acc[i][n][j] + bv;
                if constexpr (EPI == 0) {
                    // gelu(v) = v * sigmoid(2u), u = 0.79788456(v + 0.044715 v^3)
                    float w = v * v;
                    float z = v * fmaf(w, -0.0713548162f, -1.5957691216f);  // -2u
                    v = __fdividef(v, 1.0f + __expf(z));
                    outb[(gr + j) * N + gc] = f2bf(v);
                } else {
                    outf[(gr + j) * N + gc] = v;
                }
            }
        }
    }
}

// ---------- LayerNorm (in place, f32) + scatter-add into updated ----------
__global__ __launch_bounds__(256) void ln_scatter(float* __restrict__ y,
                                                  const float* __restrict__ gamma,
                                                  const float* __restrict__ beta,
                                                  const int* __restrict__ s_i,
                                                  float* __restrict__ upd) {
    const int lane = threadIdx.x & 63;
    const long row = (long)blockIdx.x * 4 + (threadIdx.x >> 6);
    const long base = row * 768;
    float v[12];
#pragma unroll
    for (int i = 0; i < 12; ++i) v[i] = y[base + i * 64 + lane];
    float s = 0.f, q = 0.f;
#pragma unroll
    for (int i = 0; i < 12; ++i) { s += v[i]; q += v[i] * v[i]; }
#pragma unroll
    for (int off = 32; off > 0; off >>= 1) {
        s += __shfl_xor(s, off, 64);
        q += __shfl_xor(q, off, 64);
    }
    const float mu = s * (1.f / 768.f);
    const float var = q * (1.f / 768.f) - mu * mu;
    const float inv = rsqrtf(var + 1e-5f);
    const long si = s_i[row];
#pragma unroll
    for (int i = 0; i < 12; ++i) {
        int c = i * 64 + lane;
        float r = (v[i] - mu) * inv * gamma[c] + beta[c];
        y[base + c] = r;
        atomicAdd(&upd[si * 768 + c], r);
    }
}

// ---------- plain float4 copy ----------
__global__ void copy4(const float4* __restrict__ s, float4* __restrict__ d, long n) {
    long i = (long)blockIdx.x * blockDim.x + threadIdx.x;
    long stride = (long)gridDim.x * blockDim.x;
    for (; i < n; i += stride) d[i] = s[i];
}

extern "C" void kernel_launch(void* const* d_in, const int* in_sizes, int n_in,
                              void* d_out, int out_size, void* d_ws, size_t ws_size,
                              hipStream_t stream) {
    const float* u_t = (const float*)d_in[0];
    const int* s_i = (const int*)d_in[1];
    const float* emb = (const float*)d_in[2];
    const float* W1 = (const float*)d_in[3];
    const float* b1 = (const float*)d_in[4];
    const float* W2 = (const float*)d_in[5];
    const float* b2 = (const float*)d_in[6];
    const float* gamma = (const float*)d_in[7];
    const float* beta = (const float*)d_in[8];

    float* out = (float*)d_out;
    float* newh = out;             // [65536,768] f32 (y, then LN in place) - NOT in upd
    float* upd = out + 50331648L;  // [262144,768] f32 (scratch first, final last)

    // scratch inside upd (all dead before copy4 runs):
    u16* base = (u16*)upd;
    u16* xb = base;                    // [65536,1536] bf16
    u16* w1b = base + 100663296L;      // [2048,1536] bf16
    u16* hbuf = base + 103809024L;     // [65536,2048] bf16
    u16* w2b = base + 238026752L;      // [768,2048] bf16

    cvtbf<<<1024, 256, 0, stream>>>((const float4*)W1, (uint2*)w1b, 786432);
    cvtbf<<<1024, 256, 0, stream>>>((const float4*)W2, (uint2*)w2b, 393216);
    xbuild<<<49152, 256, 0, stream>>>(u_t, emb, s_i, xb);
    // GEMM1: M=65536, N=2048, K=1536 -> 2048 tiles (tanh-GELU, bf16 out)
    gemm256<1536, 24, 8, 0><<<2048, 512, 0, stream>>>(xb, w1b, b1, hbuf, nullptr);
    // GEMM2: M=65536, N=768, K=2048 -> 768 tiles (bias, f32 into newh)
    gemm256<2048, 32, 3, 1><<<768, 512, 0, stream>>>(hbuf, w2b, b2, nullptr, newh);
    copy4<<<2048, 256, 0, stream>>>((const float4*)emb, (float4*)upd, 50331648L);
    ln_scatter<<<16384, 256, 0, stream>>>(newh, gamma, beta, s_i, upd);
}